// Round 1
// baseline (265.125 us; speedup 1.0000x reference)
//
#include <hip/hip_runtime.h>
#include <cstdint>
#include <cstddef>

// CrossAttentionLayer: out = softmax(Q K^T) V with Q=x1 Wq^T, K=x2 Wk^T, V=x2 Wv^T
// N1=N2=4096, D=1024, f32 in/out; internal compute fp16 MFMA (f32 accum).
//
// ws layout (bytes):
//  x1h 8M | x2h 8M | Wqh 2M | Wkh 2M | Wvh 2M | Qh 8M | Kh 8M | Vt 8M | P 32M | S 64M
//  total ~140 MB.

typedef _Float16 f16x8 __attribute__((ext_vector_type(8)));
typedef _Float16 f16x4 __attribute__((ext_vector_type(4)));
typedef float f32x4 __attribute__((ext_vector_type(4)));

__device__ __forceinline__ void gload_lds16(const _Float16* g, _Float16* l) {
  // async global->LDS, 16B per lane; LDS dest is wave-uniform base + lane*16
  __builtin_amdgcn_global_load_lds(
      (const __attribute__((address_space(1))) void*)(g),
      (__attribute__((address_space(3))) void*)(l),
      16, 0, 0);
}

// C[M,N] = A[M,K] @ B[N,K]^T  (NT GEMM), A/B fp16 row-major, C = CT (fp16 or f32).
// Tile 128x128, BK=32, 4 waves (2x2 of 64x64), mfma_f32_16x16x32_f16.
template <typename CT>
__global__ __launch_bounds__(256) void gemm_nt(const _Float16* __restrict__ A,
                                               const _Float16* __restrict__ B,
                                               CT* __restrict__ C,
                                               int M, int N, int K) {
  __shared__ _Float16 As[128 * 32];
  __shared__ _Float16 Bs[128 * 32];

  const int nbn  = N >> 7;
  const int brow = (blockIdx.x / nbn) << 7;
  const int bcol = (blockIdx.x % nbn) << 7;

  const int tid  = threadIdx.x;
  const int w    = tid >> 6;        // wave 0..3
  const int l    = tid & 63;
  const int wr   = (w >> 1) << 6;   // wave row offset in tile (0/64)
  const int wc   = (w & 1) << 6;    // wave col offset (0/64)
  const int lrow = l & 15;          // fragment row
  const int koff = (l >> 4) << 3;   // fragment k offset (0/8/16/24)

  // staging: each thread loads 16B (8 fp16); chunk (r*4+w) covers 16 rows
  const int srow = l >> 2;          // 0..15
  const int scol = (l & 3) << 3;    // 0/8/16/24

  f32x4 acc[4][4] = {};

  const _Float16* ga0 = A + (size_t)(brow + (w << 4) + srow) * K + scol;
  const _Float16* gb0 = B + (size_t)(bcol + (w << 4) + srow) * K + scol;

  for (int k0 = 0; k0 < K; k0 += 32) {
    gload_lds16(ga0 + k0,                    As + (size_t)w * 512);
    gload_lds16(ga0 + (size_t)64 * K + k0,   As + (size_t)(4 + w) * 512);
    gload_lds16(gb0 + k0,                    Bs + (size_t)w * 512);
    gload_lds16(gb0 + (size_t)64 * K + k0,   Bs + (size_t)(4 + w) * 512);
    __syncthreads();  // waits vmcnt(0): staged data visible

    f16x8 af[4], bf[4];
#pragma unroll
    for (int m = 0; m < 4; ++m)
      af[m] = *(const f16x8*)(As + ((wr + (m << 4) + lrow) << 5) + koff);
#pragma unroll
    for (int n = 0; n < 4; ++n)
      bf[n] = *(const f16x8*)(Bs + ((wc + (n << 4) + lrow) << 5) + koff);
#pragma unroll
    for (int m = 0; m < 4; ++m)
#pragma unroll
      for (int n = 0; n < 4; ++n)
        acc[m][n] = __builtin_amdgcn_mfma_f32_16x16x32_f16(af[m], bf[n], acc[m][n], 0, 0, 0);
    __syncthreads();  // all reads done before next stage
  }

  // C/D layout: col = lane&15, row = (lane>>4)*4 + j  [verified m89/m91]
  const int crow = brow + wr + ((l >> 4) << 2);
  const int ccol = bcol + wc + lrow;
#pragma unroll
  for (int m = 0; m < 4; ++m)
#pragma unroll
    for (int n = 0; n < 4; ++n)
#pragma unroll
      for (int j = 0; j < 4; ++j)
        C[(size_t)(crow + (m << 4) + j) * N + (ccol + (n << 4))] = (CT)acc[m][n][j];
}

// Row softmax: S[row, 0..N) f32 -> P fp16. One block per row, row staged in LDS.
__global__ __launch_bounds__(256) void softmax_rows(const float* __restrict__ S,
                                                    _Float16* __restrict__ P,
                                                    int N) {
  __shared__ float buf[4096];
  __shared__ float red[8];
  const int row = blockIdx.x;
  const int tid = threadIdx.x;
  const int n4  = N >> 2;
  const float4* s4 = (const float4*)(S + (size_t)row * N);
  float4* b4 = (float4*)buf;

  float m = -3.4e38f;
  for (int i = tid; i < n4; i += 256) {
    float4 v = s4[i];
    b4[i] = v;
    m = fmaxf(m, fmaxf(fmaxf(v.x, v.y), fmaxf(v.z, v.w)));
  }
  for (int off = 32; off > 0; off >>= 1) m = fmaxf(m, __shfl_xor(m, off));
  if ((tid & 63) == 0) red[tid >> 6] = m;
  __syncthreads();
  m = fmaxf(fmaxf(red[0], red[1]), fmaxf(red[2], red[3]));

  float s = 0.f;
  for (int i = tid; i < n4; i += 256) {
    float4 v = b4[i];
    v.x = __expf(v.x - m); v.y = __expf(v.y - m);
    v.z = __expf(v.z - m); v.w = __expf(v.w - m);
    b4[i] = v;
    s += (v.x + v.y) + (v.z + v.w);
  }
  for (int off = 32; off > 0; off >>= 1) s += __shfl_xor(s, off);
  if ((tid & 63) == 0) red[4 + (tid >> 6)] = s;
  __syncthreads();
  s = (red[4] + red[5]) + (red[6] + red[7]);
  const float inv = 1.f / s;

  f16x4* p4 = (f16x4*)(P + (size_t)row * N);
  for (int i = tid; i < n4; i += 256) {
    float4 v = b4[i];
    f16x4 h = { (_Float16)(v.x * inv), (_Float16)(v.y * inv),
                (_Float16)(v.z * inv), (_Float16)(v.w * inv) };
    p4[i] = h;
  }
}

__global__ __launch_bounds__(256) void cast_f32_f16(const float* __restrict__ in,
                                                    _Float16* __restrict__ out, int n4) {
  int i = blockIdx.x * 256 + threadIdx.x;
  if (i < n4) {
    float4 v = ((const float4*)in)[i];
    f16x4 h = { (_Float16)v.x, (_Float16)v.y, (_Float16)v.z, (_Float16)v.w };
    ((f16x4*)out)[i] = h;
  }
}

extern "C" void kernel_launch(void* const* d_in, const int* in_sizes, int n_in,
                              void* d_out, int out_size, void* d_ws, size_t ws_size,
                              hipStream_t stream) {
  const int D  = 1024;
  const int N1 = in_sizes[0] / D;   // 4096
  const int N2 = in_sizes[1] / D;   // 4096

  const float* x1 = (const float*)d_in[0];
  const float* x2 = (const float*)d_in[1];
  const float* Wq = (const float*)d_in[2];
  const float* Wk = (const float*)d_in[3];
  const float* Wv = (const float*)d_in[4];
  float* out = (float*)d_out;

  _Float16* x1h = (_Float16*)d_ws;
  _Float16* x2h = x1h + (size_t)N1 * D;
  _Float16* Wqh = x2h + (size_t)N2 * D;
  _Float16* Wkh = Wqh + (size_t)D * D;
  _Float16* Wvh = Wkh + (size_t)D * D;
  _Float16* Qh  = Wvh + (size_t)D * D;
  _Float16* Kh  = Qh  + (size_t)N1 * D;
  _Float16* Vt  = Kh  + (size_t)N2 * D;   // V transposed: Vt[j,i] = V[i,j]
  _Float16* P   = Vt  + (size_t)D * N2;
  float*    S   = (float*)(P + (size_t)N1 * N2);

  auto cast = [&](const float* src, _Float16* dst, size_t n) {
    int n4 = (int)(n >> 2);
    cast_f32_f16<<<dim3((n4 + 255) / 256), 256, 0, stream>>>(src, dst, n4);
  };
  cast(x1, x1h, (size_t)N1 * D);
  cast(x2, x2h, (size_t)N2 * D);
  cast(Wq, Wqh, (size_t)D * D);
  cast(Wk, Wkh, (size_t)D * D);
  cast(Wv, Wvh, (size_t)D * D);

  // Q = x1 @ Wq^T ; K = x2 @ Wk^T   (NT: both operands row-major over k)
  gemm_nt<_Float16><<<dim3((N1 / 128) * (D / 128)), 256, 0, stream>>>(x1h, Wqh, Qh, N1, D, D);
  gemm_nt<_Float16><<<dim3((N2 / 128) * (D / 128)), 256, 0, stream>>>(x2h, Wkh, Kh, N2, D, D);
  // Vt[j,i] = sum_k Wv[j,k] x2[i,k]  -> Vt = Wv @ x2^T
  gemm_nt<_Float16><<<dim3((D / 128) * (N2 / 128)), 256, 0, stream>>>(Wvh, x2h, Vt, D, N2, D);
  // S = Q @ K^T (f32 out)
  gemm_nt<float><<<dim3((N1 / 128) * (N2 / 128)), 256, 0, stream>>>(Qh, Kh, S, N1, N2, D);
  // P = softmax(S) row-wise (fp16 out)
  softmax_rows<<<dim3(N1), 256, 0, stream>>>(S, P, N2);
  // out = P @ Vt^T (f32 out to d_out)
  gemm_nt<float><<<dim3((N1 / 128) * (D / 128)), 256, 0, stream>>>(P, Vt, out, N1, D, N2);
}

// Round 2
// 210.432 us; speedup vs baseline: 1.2599x; 1.2599x over previous
//
#include <hip/hip_runtime.h>
#include <cstdint>
#include <cstddef>

typedef _Float16 f16x8 __attribute__((ext_vector_type(8)));
typedef _Float16 f16x4 __attribute__((ext_vector_type(4)));
typedef float f32x4 __attribute__((ext_vector_type(4)));

__device__ __forceinline__ void gload_lds16(const _Float16* g, _Float16* l) {
  // async global->LDS, 16B/lane; LDS dest = wave-uniform base + lane*16
  __builtin_amdgcn_global_load_lds(
      (const __attribute__((address_space(1))) void*)(g),
      (__attribute__((address_space(3))) void*)(l), 16, 0, 0);
}

// ---------------------------------------------------------------------------
// Pipelined 256x256 NT GEMM, BK=32, 8 waves (2M x 4N), fp16 in, f32 out.
// C[s][m][n] = sum_k A[m][ksOff*s + k] * B[n][ksOff*s + k], k in [0, nT*32).
// T2: XOR-swizzled LDS (swizzle applied to global src AND ds_read, same
//     involution: slot ^= (row>>1)&3). T3/T4: stage tile t+1 during tile t,
//     raw s_barrier + counted vmcnt(2), never drain in-loop. T5: setprio.
// ---------------------------------------------------------------------------
__global__ __launch_bounds__(512, 2) void gemm256(
    const _Float16* __restrict__ A, int lda,
    const _Float16* __restrict__ B, int ldb,
    float* __restrict__ C, int ldc,
    int nbm, int nbn, int nT, int ksOff, size_t cSplit) {
  __shared__ _Float16 lds[32768];  // 64 KiB: [buf(2)][A 16KB | B 16KB]

  const int inner = nbm * nbn;
  const int bid0  = blockIdx.x;
  const int s     = bid0 / inner;
  int ib          = bid0 % inner;
  // XCD-aware swizzle (inner % 8 == 0 for all our launches)
  ib = (ib & 7) * (inner >> 3) + (ib >> 3);
  const int brow = (ib / nbn) << 8;
  const int bcol = (ib % nbn) << 8;

  const _Float16* As = A + (size_t)s * ksOff;
  const _Float16* Bs = B + (size_t)s * ksOff;

  const int tid = threadIdx.x;
  const int w   = tid >> 6;   // 0..7
  const int l   = tid & 63;
  const int wm  = w >> 2;     // 0..1
  const int wn  = w & 3;      // 0..3

  // --- staging source addresses (pre-swizzled global cols, rule 21) ---
  // chunk q (1KB = 16 rows x 64B): wave w stages chunks {w, w+8} of A and B.
  // lane l: row_in_chunk = l>>2; stored slot = l&3 holds logical slot
  // (l&3) ^ ((l>>3)&3)  [= (l&3) ^ ((row>>1)&3)].
  const int sRowOff = l >> 2;
  const int sColOff = (((l & 3) ^ ((l >> 3) & 3)) << 3);  // elements
  const _Float16* gA0 = As + (size_t)(brow + (w << 4) + sRowOff) * lda + sColOff;
  const _Float16* gA1 = As + (size_t)(brow + ((w + 8) << 4) + sRowOff) * lda + sColOff;
  const _Float16* gB0 = Bs + (size_t)(bcol + (w << 4) + sRowOff) * ldb + sColOff;
  const _Float16* gB1 = Bs + (size_t)(bcol + ((w + 8) << 4) + sRowOff) * ldb + sColOff;

  // --- fragment read byte offsets (swizzled ds_read, same involution) ---
  // frag (row r, kslot l>>4): byte = r*64 + ((l>>4) ^ ((r>>1)&3))*16
  const int axr = ((l & 15) >> 1) & 3;
  const int aByteBase = (wm << 13) + ((l & 15) << 6) + (((l >> 4) ^ axr) << 4);
  const int bByteBase = (wn << 12) + ((l & 15) << 6) + (((l >> 4) ^ axr) << 4);

  f32x4 acc[8][4] = {};

  // prologue: stage tile 0 into buf 0
  gload_lds16(gA0, lds + (w << 9));
  gload_lds16(gA1, lds + ((w + 8) << 9));
  gload_lds16(gB0, lds + 8192 + (w << 9));
  gload_lds16(gB1, lds + 8192 + ((w + 8) << 9));

  for (int t = 0; t < nT; ++t) {
    const int c = t & 1;
    const char* AsCb = (const char*)(lds + c * 16384);
    const char* BsCb = AsCb + 16384;
    _Float16* AsN = lds + (c ^ 1) * 16384;
    _Float16* BsN = AsN + 8192;
    const int tn = (t + 1 < nT) ? t + 1 : t;  // clamp (redundant re-stage on last)

    __builtin_amdgcn_s_barrier();  // A: all reads of buf[c^1] (prev tile) done
    gload_lds16(gA0 + tn * 32, AsN + (w << 9));
    gload_lds16(gA1 + tn * 32, AsN + ((w + 8) << 9));
    asm volatile("s_waitcnt vmcnt(2)" ::: "memory");  // own tile-t loads landed
    __builtin_amdgcn_s_barrier();  // B: everyone's tile-t loads landed
    asm volatile("" ::: "memory");
    __builtin_amdgcn_sched_barrier(0);

    f16x8 bf[4], af[4];
#pragma unroll
    for (int n = 0; n < 4; ++n)
      bf[n] = *(const f16x8*)(BsCb + bByteBase + (n << 10));
#pragma unroll
    for (int m = 0; m < 4; ++m)
      af[m] = *(const f16x8*)(AsCb + aByteBase + (m << 10));
    __builtin_amdgcn_s_setprio(1);
#pragma unroll
    for (int m = 0; m < 4; ++m)
#pragma unroll
      for (int n = 0; n < 4; ++n)
        acc[m][n] = __builtin_amdgcn_mfma_f32_16x16x32_f16(af[m], bf[n], acc[m][n], 0, 0, 0);
    __builtin_amdgcn_s_setprio(0);

    // phase 1: stage B of tile t+1, compute m=4..7
    gload_lds16(gB0 + tn * 32, BsN + (w << 9));
    gload_lds16(gB1 + tn * 32, BsN + ((w + 8) << 9));
#pragma unroll
    for (int m = 0; m < 4; ++m)
      af[m] = *(const f16x8*)(AsCb + aByteBase + ((m + 4) << 10));
    __builtin_amdgcn_s_setprio(1);
#pragma unroll
    for (int m = 0; m < 4; ++m)
#pragma unroll
      for (int n = 0; n < 4; ++n)
        acc[m + 4][n] = __builtin_amdgcn_mfma_f32_16x16x32_f16(af[m], bf[n], acc[m + 4][n], 0, 0, 0);
    __builtin_amdgcn_s_setprio(0);
  }
  asm volatile("s_waitcnt vmcnt(0)" ::: "memory");  // drain strays before exit

  // epilogue: C/D layout col=lane&15, row=(lane>>4)*4+j
  float* Cb = C + (size_t)s * cSplit;
  const int crow0 = brow + (wm << 7) + ((l >> 4) << 2);
  const int ccol  = bcol + (wn << 6) + (l & 15);
#pragma unroll
  for (int m = 0; m < 8; ++m)
#pragma unroll
    for (int n = 0; n < 4; ++n)
#pragma unroll
      for (int j = 0; j < 4; ++j)
        Cb[(size_t)(crow0 + (m << 4) + j) * ldc + ccol + (n << 4)] = acc[m][n][j];
}

// ---------------------------------------------------------------------------
// Simple 128x128 NT GEMM (round-1, verified) — used for the QKV projections.
// ---------------------------------------------------------------------------
template <typename CT>
__global__ __launch_bounds__(256) void gemm_nt(const _Float16* __restrict__ A,
                                               const _Float16* __restrict__ B,
                                               CT* __restrict__ C,
                                               int M, int N, int K) {
  __shared__ _Float16 Asb[128 * 32];
  __shared__ _Float16 Bsb[128 * 32];

  const int nbn  = N >> 7;
  const int brow = (blockIdx.x / nbn) << 7;
  const int bcol = (blockIdx.x % nbn) << 7;

  const int tid  = threadIdx.x;
  const int w    = tid >> 6;
  const int l    = tid & 63;
  const int wr   = (w >> 1) << 6;
  const int wc   = (w & 1) << 6;
  const int lrow = l & 15;
  const int koff = (l >> 4) << 3;
  const int srow = l >> 2;
  const int scol = (l & 3) << 3;

  f32x4 acc[4][4] = {};

  const _Float16* ga0 = A + (size_t)(brow + (w << 4) + srow) * K + scol;
  const _Float16* gb0 = B + (size_t)(bcol + (w << 4) + srow) * K + scol;

  for (int k0 = 0; k0 < K; k0 += 32) {
    gload_lds16(ga0 + k0,                  Asb + (size_t)w * 512);
    gload_lds16(ga0 + (size_t)64 * K + k0, Asb + (size_t)(4 + w) * 512);
    gload_lds16(gb0 + k0,                  Bsb + (size_t)w * 512);
    gload_lds16(gb0 + (size_t)64 * K + k0, Bsb + (size_t)(4 + w) * 512);
    __syncthreads();

    f16x8 af[4], bf[4];
#pragma unroll
    for (int m = 0; m < 4; ++m)
      af[m] = *(const f16x8*)(Asb + ((wr + (m << 4) + lrow) << 5) + koff);
#pragma unroll
    for (int n = 0; n < 4; ++n)
      bf[n] = *(const f16x8*)(Bsb + ((wc + (n << 4) + lrow) << 5) + koff);
#pragma unroll
    for (int m = 0; m < 4; ++m)
#pragma unroll
      for (int n = 0; n < 4; ++n)
        acc[m][n] = __builtin_amdgcn_mfma_f32_16x16x32_f16(af[m], bf[n], acc[m][n], 0, 0, 0);
    __syncthreads();
  }

  const int crow = brow + wr + ((l >> 4) << 2);
  const int ccol = bcol + wc + lrow;
#pragma unroll
  for (int m = 0; m < 4; ++m)
#pragma unroll
    for (int n = 0; n < 4; ++n)
#pragma unroll
      for (int j = 0; j < 4; ++j)
        C[(size_t)(crow + (m << 4) + j) * N + (ccol + (n << 4))] = (CT)acc[m][n][j];
}

// Row softmax: S[row, 0..N) f32 -> P fp16.
__global__ __launch_bounds__(256) void softmax_rows(const float* __restrict__ S,
                                                    _Float16* __restrict__ P,
                                                    int N) {
  __shared__ float buf[4096];
  __shared__ float red[8];
  const int row = blockIdx.x;
  const int tid = threadIdx.x;
  const int n4  = N >> 2;
  const float4* s4 = (const float4*)(S + (size_t)row * N);
  float4* b4 = (float4*)buf;

  float m = -3.4e38f;
  for (int i = tid; i < n4; i += 256) {
    float4 v = s4[i];
    b4[i] = v;
    m = fmaxf(m, fmaxf(fmaxf(v.x, v.y), fmaxf(v.z, v.w)));
  }
  for (int off = 32; off > 0; off >>= 1) m = fmaxf(m, __shfl_xor(m, off));
  if ((tid & 63) == 0) red[tid >> 6] = m;
  __syncthreads();
  m = fmaxf(fmaxf(red[0], red[1]), fmaxf(red[2], red[3]));

  float sum = 0.f;
  for (int i = tid; i < n4; i += 256) {
    float4 v = b4[i];
    v.x = __expf(v.x - m); v.y = __expf(v.y - m);
    v.z = __expf(v.z - m); v.w = __expf(v.w - m);
    b4[i] = v;
    sum += (v.x + v.y) + (v.z + v.w);
  }
  for (int off = 32; off > 0; off >>= 1) sum += __shfl_xor(sum, off);
  if ((tid & 63) == 0) red[4 + (tid >> 6)] = sum;
  __syncthreads();
  sum = (red[4] + red[5]) + (red[6] + red[7]);
  const float inv = 1.f / sum;

  f16x4* p4 = (f16x4*)(P + (size_t)row * N);
  for (int i = tid; i < n4; i += 256) {
    float4 v = b4[i];
    f16x4 h = { (_Float16)(v.x * inv), (_Float16)(v.y * inv),
                (_Float16)(v.z * inv), (_Float16)(v.w * inv) };
    p4[i] = h;
  }
}

__global__ __launch_bounds__(256) void cast_f32_f16(const float* __restrict__ in,
                                                    _Float16* __restrict__ out, int n4) {
  int i = blockIdx.x * 256 + threadIdx.x;
  if (i < n4) {
    float4 v = ((const float4*)in)[i];
    f16x4 h = { (_Float16)v.x, (_Float16)v.y, (_Float16)v.z, (_Float16)v.w };
    ((f16x4*)out)[i] = h;
  }
}

// out[i] = sum over 4 split-K partials (deterministic reduction)
__global__ __launch_bounds__(256) void reduce4(const float* __restrict__ p,
                                               float* __restrict__ out,
                                               int n4, size_t stride4) {
  int i = blockIdx.x * 256 + threadIdx.x;
  if (i >= n4) return;
  const float4* p4 = (const float4*)p;
  float4 a = p4[i];
  float4 b = p4[i + stride4];
  float4 c = p4[i + 2 * stride4];
  float4 d = p4[i + 3 * stride4];
  float4 r = { (a.x + b.x) + (c.x + d.x), (a.y + b.y) + (c.y + d.y),
               (a.z + b.z) + (c.z + d.z), (a.w + b.w) + (c.w + d.w) };
  ((float4*)out)[i] = r;
}

extern "C" void kernel_launch(void* const* d_in, const int* in_sizes, int n_in,
                              void* d_out, int out_size, void* d_ws, size_t ws_size,
                              hipStream_t stream) {
  const int D  = 1024;
  const int N1 = in_sizes[0] / D;   // 4096
  const int N2 = in_sizes[1] / D;   // 4096

  const float* x1 = (const float*)d_in[0];
  const float* x2 = (const float*)d_in[1];
  const float* Wq = (const float*)d_in[2];
  const float* Wk = (const float*)d_in[3];
  const float* Wv = (const float*)d_in[4];
  float* out = (float*)d_out;

  _Float16* x1h = (_Float16*)d_ws;
  _Float16* x2h = x1h + (size_t)N1 * D;
  _Float16* Wqh = x2h + (size_t)N2 * D;
  _Float16* Wkh = Wqh + (size_t)D * D;
  _Float16* Wvh = Wkh + (size_t)D * D;
  _Float16* Qh  = Wvh + (size_t)D * D;
  _Float16* Kh  = Qh  + (size_t)N1 * D;
  _Float16* Vt  = Kh  + (size_t)N2 * D;   // V transposed: Vt[j,i] = V[i,j]
  _Float16* P   = Vt  + (size_t)D * N2;
  float*    S   = (float*)(P + (size_t)N1 * N2);  // 64MB; reused as PV partials

  auto cast = [&](const float* src, _Float16* dst, size_t n) {
    int n4 = (int)(n >> 2);
    cast_f32_f16<<<dim3((n4 + 255) / 256), 256, 0, stream>>>(src, dst, n4);
  };
  cast(x1, x1h, (size_t)N1 * D);
  cast(x2, x2h, (size_t)N2 * D);
  cast(Wq, Wqh, (size_t)D * D);
  cast(Wk, Wkh, (size_t)D * D);
  cast(Wv, Wvh, (size_t)D * D);

  // QKV projections (128^2 tile, verified round-1 path)
  gemm_nt<_Float16><<<dim3((N1 / 128) * (D / 128)), 256, 0, stream>>>(x1h, Wqh, Qh, N1, D, D);
  gemm_nt<_Float16><<<dim3((N2 / 128) * (D / 128)), 256, 0, stream>>>(x2h, Wkh, Kh, N2, D, D);
  gemm_nt<_Float16><<<dim3((D / 128) * (N2 / 128)), 256, 0, stream>>>(Wvh, x2h, Vt, D, N2, D);

  // S = Q @ K^T : 256^2 pipelined, grid 16x16 = 256 blocks (1/CU)
  gemm256<<<dim3(256), 512, 0, stream>>>(Qh, D, Kh, D, S, N2,
                                         N1 / 256, N2 / 256, D / 32, 0, 0);
  // P = softmax(S)
  softmax_rows<<<dim3(N1), 256, 0, stream>>>(S, P, N2);
  // PV: split-K=4 partials into S-buffer (dead after softmax), then reduce.
  // partial[s] = P[:, s*1024:+1024] @ Vt[:, s*1024:+1024]^T
  gemm256<<<dim3(256), 512, 0, stream>>>(P, N2, Vt, N2, S, D,
                                         N1 / 256, D / 256, 1024 / 32, 1024,
                                         (size_t)N1 * D);
  reduce4<<<dim3((N1 * D / 4 + 255) / 256), 256, 0, stream>>>(
      S, out, N1 * D / 4, (size_t)N1 * D / 4);
}

// Round 3
// 167.061 us; speedup vs baseline: 1.5870x; 1.2596x over previous
//
#include <hip/hip_runtime.h>
#include <cstdint>
#include <cstddef>

typedef _Float16 f16x8 __attribute__((ext_vector_type(8)));
typedef _Float16 f16x4 __attribute__((ext_vector_type(4)));
typedef float f32x4 __attribute__((ext_vector_type(4)));

__device__ __forceinline__ void gload_lds16(const _Float16* g, void* l) {
  // async global->LDS, 16B/lane; LDS dest = wave-uniform base + lane*16
  __builtin_amdgcn_global_load_lds(
      (const __attribute__((address_space(1))) void*)(g),
      (__attribute__((address_space(3))) void*)(l), 16, 0, 0);
}

struct GDesc {
  const _Float16* A;  // [M][K] row-major, lda
  const _Float16* B;  // [N][K] row-major, ldb
  void* C;            // [M][N] row-major, ldc
  int lda, ldb, ldc, nbm, nbn;
};

// ---------------------------------------------------------------------------
// Deep-pipelined 256x256 NT GEMM, BK=32, quad-buffered LDS (128 KB).
// 8 waves (2M x 4N), per-wave output 128x64. Per K-tile: 2 phases x 16 MFMA.
// Stage K-tile j+3 during tile j (2 gload_lds/phase); vmcnt(8) at tile
// boundary only (2 tiles in flight). Zero-conflict XOR swizzle (R2-verified):
// phys 16B slot p = q ^ ((row>>1)&3), applied to global src AND ds_read.
// MULTI: blockIdx range selects one of 3 descriptors (fused QKV).
// !MULTI: gi = split-K index (A,B += gi*ksOff; C += gi*cSplit).
// Requires nKT >= 3.
// ---------------------------------------------------------------------------
template <typename CT, bool MULTI>
__global__ __launch_bounds__(512, 2) void gemmq(
    GDesc d0, GDesc d1, GDesc d2,
    int inner, int nKT, int ksOff, size_t cSplit) {
  __shared__ __align__(16) char smem[131072];  // 4 bufs x (A 16KB | B 16KB)

  const int bid = blockIdx.x;
  const int gi  = bid / inner;
  int ib        = bid % inner;

  GDesc d = d0;
  if (MULTI) { if (gi == 1) d = d1; else if (gi == 2) d = d2; }
  const _Float16* A = d.A;
  const _Float16* B = d.B;
  CT* C = (CT*)d.C;
  if (!MULTI) {
    A += (size_t)gi * ksOff;
    B += (size_t)gi * ksOff;
    C += (size_t)gi * cSplit;
  }
  const int lda = d.lda, ldb = d.ldb, ldc = d.ldc, nbn = d.nbn;

  // XCD-aware swizzle (inner % 8 == 0 for all launches)
  ib = (ib & 7) * (inner >> 3) + (ib >> 3);
  const int brow = (ib / nbn) << 8;
  const int bcol = (ib % nbn) << 8;

  const int tid = threadIdx.x;
  const int w   = tid >> 6;   // 0..7
  const int l   = tid & 63;
  const int wm  = w >> 2;     // 0..1
  const int wn  = w & 3;      // 0..3

  // staging: chunk = 16 rows x 64B; wave w stages chunks {w, w+8} of A and B.
  // lane l -> row_in_chunk = l>>2, phys slot = l&3; global logical slot
  // q = (l&3) ^ ((l>>3)&3)  [inverse of read swizzle].
  const int sRow = l >> 2;
  const int sCol = (((l & 3) ^ ((l >> 3) & 3)) << 3);  // element offset
  const _Float16* gA0 = A + (size_t)(brow + (w << 4) + sRow) * lda + sCol;
  const _Float16* gA1 = A + (size_t)(brow + ((w + 8) << 4) + sRow) * lda + sCol;
  const _Float16* gB0 = B + (size_t)(bcol + (w << 4) + sRow) * ldb + sCol;
  const _Float16* gB1 = B + (size_t)(bcol + ((w + 8) << 4) + sRow) * ldb + sCol;

  // fragment read offsets (swizzled): frag row r, kslot l>>4:
  // byte = r*64 + ((l>>4) ^ ((r>>1)&3))*16
  const int axr = (l >> 1) & 3;
  const int fq  = ((l >> 4) ^ axr) << 4;
  const int aBase = (wm << 13) + ((l & 15) << 6) + fq;  // within A region
  const int bBase = (wn << 12) + ((l & 15) << 6) + fq;  // within B region

  f32x4 acc[8][4] = {};

  // prologue: stage tiles 0,1,2
#pragma unroll
  for (int t = 0; t < 3; ++t) {
    char* Ab = smem + t * 32768;
    char* Bb = Ab + 16384;
    gload_lds16(gA0 + t * 32, Ab + (w << 10));
    gload_lds16(gA1 + t * 32, Ab + ((w + 8) << 10));
    gload_lds16(gB0 + t * 32, Bb + (w << 10));
    gload_lds16(gB1 + t * 32, Bb + ((w + 8) << 10));
  }
  asm volatile("s_waitcnt vmcnt(8)" ::: "memory");  // tile 0 landed
  __builtin_amdgcn_s_barrier();
  __builtin_amdgcn_sched_barrier(0);

  for (int j = 0; j < nKT; ++j) {
    const char* Ab = smem + (j & 3) * 32768;
    const char* Bb = Ab + 16384;
    const int jn = j + 3;
    char* AbN = smem + (jn & 3) * 32768;
    char* BbN = AbN + 16384;
    const bool st = (jn < nKT);

    // ---- phase 0: stage A(j+3) | read B n0-3, A m0-3 | MFMA m0-3 ----
    if (st) {
      gload_lds16(gA0 + jn * 32, AbN + (w << 10));
      gload_lds16(gA1 + jn * 32, AbN + ((w + 8) << 10));
    }
    f16x8 bf[4], af[4];
#pragma unroll
    for (int n = 0; n < 4; ++n)
      bf[n] = *(const f16x8*)(Bb + bBase + (n << 10));
#pragma unroll
    for (int m = 0; m < 4; ++m)
      af[m] = *(const f16x8*)(Ab + aBase + (m << 10));
    __builtin_amdgcn_s_barrier();
    __builtin_amdgcn_s_setprio(1);
#pragma unroll
    for (int m = 0; m < 4; ++m)
#pragma unroll
      for (int n = 0; n < 4; ++n)
        acc[m][n] = __builtin_amdgcn_mfma_f32_16x16x32_f16(af[m], bf[n], acc[m][n], 0, 0, 0);
    __builtin_amdgcn_s_setprio(0);
    __builtin_amdgcn_s_barrier();
    __builtin_amdgcn_sched_barrier(0);

    // ---- phase 1: stage B(j+3) | read A m4-7 | MFMA m4-7 ----
    if (st) {
      gload_lds16(gB0 + jn * 32, BbN + (w << 10));
      gload_lds16(gB1 + jn * 32, BbN + ((w + 8) << 10));
    }
#pragma unroll
    for (int m = 0; m < 4; ++m)
      af[m] = *(const f16x8*)(Ab + aBase + ((m + 4) << 10));
    __builtin_amdgcn_s_barrier();
    __builtin_amdgcn_s_setprio(1);
#pragma unroll
    for (int m = 0; m < 4; ++m)
#pragma unroll
      for (int n = 0; n < 4; ++n)
        acc[m + 4][n] = __builtin_amdgcn_mfma_f32_16x16x32_f16(af[m], bf[n], acc[m + 4][n], 0, 0, 0);
    __builtin_amdgcn_s_setprio(0);
    // tile boundary: allow tiles j+2,j+3 (8 loads) in flight; j+1 landed
    asm volatile("s_waitcnt vmcnt(8)" ::: "memory");
    __builtin_amdgcn_s_barrier();
    __builtin_amdgcn_sched_barrier(0);
  }
  asm volatile("s_waitcnt vmcnt(0)" ::: "memory");  // drain strays

  // epilogue: C/D layout col=lane&15, row=(lane>>4)*4+jj
  const int crow0 = brow + (wm << 7) + ((l >> 4) << 2);
  const int ccol  = bcol + (wn << 6) + (l & 15);
#pragma unroll
  for (int m = 0; m < 8; ++m)
#pragma unroll
    for (int n = 0; n < 4; ++n)
#pragma unroll
      for (int jj = 0; jj < 4; ++jj)
        C[(size_t)(crow0 + (m << 4) + jj) * ldc + ccol + (n << 4)] = (CT)acc[m][n][jj];
}

// Row softmax: S[row, 0..N) f32 -> P fp16.
__global__ __launch_bounds__(256) void softmax_rows(const float* __restrict__ S,
                                                    _Float16* __restrict__ P,
                                                    int N) {
  __shared__ float buf[4096];
  __shared__ float red[8];
  const int row = blockIdx.x;
  const int tid = threadIdx.x;
  const int n4  = N >> 2;
  const float4* s4 = (const float4*)(S + (size_t)row * N);
  float4* b4 = (float4*)buf;

  float m = -3.4e38f;
  for (int i = tid; i < n4; i += 256) {
    float4 v = s4[i];
    b4[i] = v;
    m = fmaxf(m, fmaxf(fmaxf(v.x, v.y), fmaxf(v.z, v.w)));
  }
  for (int off = 32; off > 0; off >>= 1) m = fmaxf(m, __shfl_xor(m, off));
  if ((tid & 63) == 0) red[tid >> 6] = m;
  __syncthreads();
  m = fmaxf(fmaxf(red[0], red[1]), fmaxf(red[2], red[3]));

  float sum = 0.f;
  for (int i = tid; i < n4; i += 256) {
    float4 v = b4[i];
    v.x = __expf(v.x - m); v.y = __expf(v.y - m);
    v.z = __expf(v.z - m); v.w = __expf(v.w - m);
    b4[i] = v;
    sum += (v.x + v.y) + (v.z + v.w);
  }
  for (int off = 32; off > 0; off >>= 1) sum += __shfl_xor(sum, off);
  if ((tid & 63) == 0) red[4 + (tid >> 6)] = sum;
  __syncthreads();
  sum = (red[4] + red[5]) + (red[6] + red[7]);
  const float inv = 1.f / sum;

  f16x4* p4 = (f16x4*)(P + (size_t)row * N);
  for (int i = tid; i < n4; i += 256) {
    float4 v = b4[i];
    f16x4 h = { (_Float16)(v.x * inv), (_Float16)(v.y * inv),
                (_Float16)(v.z * inv), (_Float16)(v.w * inv) };
    p4[i] = h;
  }
}

__global__ __launch_bounds__(256) void cast_f32_f16(const float* __restrict__ in,
                                                    _Float16* __restrict__ out, int n4) {
  int i = blockIdx.x * 256 + threadIdx.x;
  if (i < n4) {
    float4 v = ((const float4*)in)[i];
    f16x4 h = { (_Float16)v.x, (_Float16)v.y, (_Float16)v.z, (_Float16)v.w };
    ((f16x4*)out)[i] = h;
  }
}

// out[i] = sum of 4 split-K partials (deterministic)
__global__ __launch_bounds__(256) void reduce4(const float* __restrict__ p,
                                               float* __restrict__ out,
                                               int n4, size_t stride4) {
  int i = blockIdx.x * 256 + threadIdx.x;
  if (i >= n4) return;
  const float4* p4 = (const float4*)p;
  float4 a = p4[i];
  float4 b = p4[i + stride4];
  float4 c = p4[i + 2 * stride4];
  float4 d = p4[i + 3 * stride4];
  float4 r = { (a.x + b.x) + (c.x + d.x), (a.y + b.y) + (c.y + d.y),
               (a.z + b.z) + (c.z + d.z), (a.w + b.w) + (c.w + d.w) };
  ((float4*)out)[i] = r;
}

extern "C" void kernel_launch(void* const* d_in, const int* in_sizes, int n_in,
                              void* d_out, int out_size, void* d_ws, size_t ws_size,
                              hipStream_t stream) {
  const int D  = 1024;
  const int N1 = in_sizes[0] / D;   // 4096
  const int N2 = in_sizes[1] / D;   // 4096

  const float* x1 = (const float*)d_in[0];
  const float* x2 = (const float*)d_in[1];
  const float* Wq = (const float*)d_in[2];
  const float* Wk = (const float*)d_in[3];
  const float* Wv = (const float*)d_in[4];
  float* out = (float*)d_out;

  _Float16* x1h = (_Float16*)d_ws;
  _Float16* x2h = x1h + (size_t)N1 * D;
  _Float16* Wqh = x2h + (size_t)N2 * D;
  _Float16* Wkh = Wqh + (size_t)D * D;
  _Float16* Wvh = Wkh + (size_t)D * D;
  _Float16* Qh  = Wvh + (size_t)D * D;
  _Float16* Kh  = Qh  + (size_t)N1 * D;
  _Float16* Vt  = Kh  + (size_t)N2 * D;   // Vt[j,i] = V[i,j]
  _Float16* P   = Vt  + (size_t)D * N2;
  float*    S   = (float*)(P + (size_t)N1 * N2);  // 64MB; reused as PV partials

  auto cast = [&](const float* src, _Float16* dst, size_t n) {
    int n4 = (int)(n >> 2);
    cast_f32_f16<<<dim3((n4 + 255) / 256), 256, 0, stream>>>(src, dst, n4);
  };
  cast(x1, x1h, (size_t)N1 * D);
  cast(x2, x2h, (size_t)N2 * D);
  cast(Wq, Wqh, (size_t)D * D);
  cast(Wk, Wkh, (size_t)D * D);
  cast(Wv, Wvh, (size_t)D * D);

  // Fused QKV projections: one 192-block dispatch, 64 blocks per GEMM.
  // Q = x1 Wq^T [4096x1024], K = x2 Wk^T [4096x1024], Vt = Wv x2^T [1024x4096]
  {
    GDesc dq = { x1h, Wqh, Qh, D, D, D, N1 / 256, D / 256 };
    GDesc dk = { x2h, Wkh, Kh, D, D, D, N2 / 256, D / 256 };
    GDesc dv = { Wvh, x2h, Vt, D, D, N2, D / 256, N2 / 256 };
    gemmq<_Float16, true><<<dim3(192), 512, 0, stream>>>(dq, dk, dv, 64, D / 32, 0, 0);
  }
  // S = Q K^T [4096x4096] f32, grid 256 (1 block/CU)
  {
    GDesc dsd = { Qh, Kh, S, D, D, N2, N1 / 256, N2 / 256 };
    gemmq<float, false><<<dim3(256), 512, 0, stream>>>(dsd, dsd, dsd, 256, D / 32, 0, 0);
  }
  // P = softmax(S)
  softmax_rows<<<dim3(N1), 256, 0, stream>>>(S, P, N2);
  // PV split-K=4: partial[s] = P[:, s*1024:+1024] @ Vt[:, s*1024:+1024]^T
  {
    GDesc dp = { P, Vt, S, N2, N2, D, N1 / 256, D / 256 };
    gemmq<float, false><<<dim3(256), 512, 0, stream>>>(dp, dp, dp, 64, 1024 / 32, 1024,
                                                       (size_t)N1 * D);
  }
  reduce4<<<dim3((N1 * D / 4 + 255) / 256), 256, 0, stream>>>(
      S, out, N1 * D / 4, (size_t)N1 * D / 4);
}

// Round 4
// 162.434 us; speedup vs baseline: 1.6322x; 1.0285x over previous
//
#include <hip/hip_runtime.h>
#include <cstdint>
#include <cstddef>

typedef _Float16 f16x8 __attribute__((ext_vector_type(8)));
typedef _Float16 f16x4 __attribute__((ext_vector_type(4)));
typedef float f32x4 __attribute__((ext_vector_type(4)));

__device__ __forceinline__ void gload_lds16(const _Float16* g, void* l) {
  // async global->LDS, 16B/lane; LDS dest = wave-uniform base + lane*16
  __builtin_amdgcn_global_load_lds(
      (const __attribute__((address_space(1))) void*)(g),
      (__attribute__((address_space(3))) void*)(l), 16, 0, 0);
}

struct GDesc {
  const _Float16* A;  // [M][K] row-major, lda
  const _Float16* B;  // [N][K] row-major, ldb
  void* C;            // [M][N] row-major, ldc
  int lda, ldb, ldc, nbm, nbn;
};

struct SetA { f16x8 b[4]; f16x8 a[4]; };  // B frags n0-3 + A frags m0-3 (8 reads)
struct SetB { f16x8 a[4]; };              // A frags m4-7 (4 reads)

// ---------------------------------------------------------------------------
// 256x256 NT GEMM, BK=32, 4 LDS buffers (128 KB), 8 waves (2M x 4N).
// Schedule (T3+T4 on BOTH counters): per K-tile ONE barrier; counted
// vmcnt(4) (2 tiles of gloads in flight, never drained); fragments
// double-buffered in registers with counted lgkmcnt(4)/(8) so each wave's
// ds_reads are serviced WHILE its MFMA clusters execute.
// Zero-conflict XOR swizzle (R2/R3-verified, SQ_LDS_BANK_CONFLICT=0):
// phys 16B slot p = q ^ ((row>>1)&3) on both the global src and ds_read.
// Invariants per wave: at tile entry, 8 ds_reads (SA of this tile) and
// 8 gloads (tiles t+1, t+2) outstanding.
// ---------------------------------------------------------------------------
__device__ __forceinline__ void tile_body(
    int t, int nKT, SetA& cur, SetA& nxt, SetB& sbv, char* smem,
    const _Float16* gA0, const _Float16* gA1,
    const _Float16* gB0, const _Float16* gB1,
    int w, int aBase, int bBase, f32x4 (&acc)[8][4]) {
  asm volatile("s_waitcnt vmcnt(4)" ::: "memory");  // tile t+1 landed
  __builtin_amdgcn_s_barrier();  // all waves' reads of buf (t-1) done
  // stage tile t+3 into buf (t+3)&3 (clamped tail: byte-identical re-stage)
  const int jc = (t + 3 < nKT) ? t + 3 : nKT - 1;
  char* dst = smem + (jc & 3) * 32768;
  gload_lds16(gA0 + jc * 32, dst + (w << 10));
  gload_lds16(gA1 + jc * 32, dst + ((w + 8) << 10));
  gload_lds16(gB0 + jc * 32, dst + 16384 + (w << 10));
  gload_lds16(gB1 + jc * 32, dst + 16384 + ((w + 8) << 10));

  const char* Ab = smem + (t & 3) * 32768;
#pragma unroll
  for (int m = 0; m < 4; ++m)
    sbv.a[m] = *(const f16x8*)(Ab + aBase + ((m + 4) << 10));
  asm volatile("s_waitcnt lgkmcnt(4)" ::: "memory");  // SA(t) done; SB in flight
  __builtin_amdgcn_sched_barrier(0);

  const char* AbN = smem + ((t + 1) & 3) * 32768;  // stale at t==nKT-1: unused
  const char* BbN = AbN + 16384;
#pragma unroll
  for (int n = 0; n < 4; ++n)
    nxt.b[n] = *(const f16x8*)(BbN + bBase + (n << 10));
#pragma unroll
  for (int m = 0; m < 4; ++m)
    nxt.a[m] = *(const f16x8*)(AbN + aBase + (m << 10));
  __builtin_amdgcn_sched_barrier(0);

  __builtin_amdgcn_s_setprio(1);
#pragma unroll
  for (int m = 0; m < 4; ++m)
#pragma unroll
    for (int n = 0; n < 4; ++n)
      acc[m][n] = __builtin_amdgcn_mfma_f32_16x16x32_f16(cur.a[m], cur.b[n], acc[m][n], 0, 0, 0);
  __builtin_amdgcn_s_setprio(0);
  asm volatile("s_waitcnt lgkmcnt(8)" ::: "memory");  // SB(t) done; SA(t+1) in flight
  __builtin_amdgcn_sched_barrier(0);
  __builtin_amdgcn_s_setprio(1);
#pragma unroll
  for (int m = 0; m < 4; ++m)
#pragma unroll
    for (int n = 0; n < 4; ++n)
      acc[m + 4][n] = __builtin_amdgcn_mfma_f32_16x16x32_f16(sbv.a[m], cur.b[n], acc[m + 4][n], 0, 0, 0);
  __builtin_amdgcn_s_setprio(0);
}

template <typename CT, bool MULTI>
__global__ __launch_bounds__(512, 2) void gemmq(
    GDesc d0, GDesc d1, GDesc d2,
    int inner, int nKT, int ksOff, size_t cSplit) {
  __shared__ __align__(16) char smem[131072];  // 4 bufs x (A 16KB | B 16KB)

  const int bid = blockIdx.x;
  const int gi  = bid / inner;
  int ib        = bid % inner;

  GDesc d = d0;
  if (MULTI) { if (gi == 1) d = d1; else if (gi == 2) d = d2; }
  const _Float16* A = d.A;
  const _Float16* B = d.B;
  CT* C = (CT*)d.C;
  if (!MULTI) {
    A += (size_t)gi * ksOff;
    B += (size_t)gi * ksOff;
    C += (size_t)gi * cSplit;
  }
  const int lda = d.lda, ldb = d.ldb, ldc = d.ldc, nbn = d.nbn;

  // XCD-aware swizzle (inner % 8 == 0 for all launches)
  ib = (ib & 7) * (inner >> 3) + (ib >> 3);
  const int brow = (ib / nbn) << 8;
  const int bcol = (ib % nbn) << 8;

  const int tid = threadIdx.x;
  const int w   = tid >> 6;   // 0..7
  const int l   = tid & 63;
  const int wm  = w >> 2;     // 0..1
  const int wn  = w & 3;      // 0..3

  // staging: chunk = 16 rows x 64B; wave w stages chunks {w, w+8} of A and B.
  // lane l -> row_in_chunk = l>>2, phys slot = l&3; global logical slot
  // q = (l&3) ^ ((l>>3)&3)  [inverse of read swizzle].
  const int sRow = l >> 2;
  const int sCol = (((l & 3) ^ ((l >> 3) & 3)) << 3);
  const _Float16* gA0 = A + (size_t)(brow + (w << 4) + sRow) * lda + sCol;
  const _Float16* gA1 = A + (size_t)(brow + ((w + 8) << 4) + sRow) * lda + sCol;
  const _Float16* gB0 = B + (size_t)(bcol + (w << 4) + sRow) * ldb + sCol;
  const _Float16* gB1 = B + (size_t)(bcol + ((w + 8) << 4) + sRow) * ldb + sCol;

  // fragment read offsets (swizzled): frag row r=l&15, kslot l>>4:
  // byte = r*64 + ((l>>4) ^ ((r>>1)&3))*16
  const int axr = (l >> 1) & 3;
  const int fq  = ((l >> 4) ^ axr) << 4;
  const int aBase = (wm << 13) + ((l & 15) << 6) + fq;
  const int bBase = (wn << 12) + ((l & 15) << 6) + fq;

  f32x4 acc[8][4] = {};
  SetA s0, s1;
  SetB sbv;

  // prologue: stage tiles 0,1,2
#pragma unroll
  for (int tt = 0; tt < 3; ++tt) {
    char* dst = smem + tt * 32768;
    gload_lds16(gA0 + tt * 32, dst + (w << 10));
    gload_lds16(gA1 + tt * 32, dst + ((w + 8) << 10));
    gload_lds16(gB0 + tt * 32, dst + 16384 + (w << 10));
    gload_lds16(gB1 + tt * 32, dst + 16384 + ((w + 8) << 10));
  }
  asm volatile("s_waitcnt vmcnt(8)" ::: "memory");  // tile 0 landed (own portion)
  __builtin_amdgcn_s_barrier();                     // everyone's portion landed
  {
    const char* Ab = smem;
    const char* Bb = smem + 16384;
#pragma unroll
    for (int n = 0; n < 4; ++n) s0.b[n] = *(const f16x8*)(Bb + bBase + (n << 10));
#pragma unroll
    for (int m = 0; m < 4; ++m) s0.a[m] = *(const f16x8*)(Ab + aBase + (m << 10));
  }

  for (int t = 0; t < nKT; t += 2) {  // nKT even
    tile_body(t,     nKT, s0, s1, sbv, smem, gA0, gA1, gB0, gB1, w, aBase, bBase, acc);
    tile_body(t + 1, nKT, s1, s0, sbv, smem, gA0, gA1, gB0, gB1, w, aBase, bBase, acc);
  }
  asm volatile("s_waitcnt vmcnt(0) lgkmcnt(0)" ::: "memory");

  // epilogue: C/D layout col=lane&15, row=(lane>>4)*4+jj
  const int crow0 = brow + (wm << 7) + ((l >> 4) << 2);
  const int ccol  = bcol + (wn << 6) + (l & 15);
#pragma unroll
  for (int m = 0; m < 8; ++m)
#pragma unroll
    for (int n = 0; n < 4; ++n)
#pragma unroll
      for (int jj = 0; jj < 4; ++jj)
        C[(size_t)(crow0 + (m << 4) + jj) * ldc + ccol + (n << 4)] = (CT)acc[m][n][jj];
}

// Row softmax: S[row, 0..N) f32 -> P fp16.
__global__ __launch_bounds__(256) void softmax_rows(const float* __restrict__ S,
                                                    _Float16* __restrict__ P,
                                                    int N) {
  __shared__ float buf[4096];
  __shared__ float red[8];
  const int row = blockIdx.x;
  const int tid = threadIdx.x;
  const int n4  = N >> 2;
  const float4* s4 = (const float4*)(S + (size_t)row * N);
  float4* b4 = (float4*)buf;

  float m = -3.4e38f;
  for (int i = tid; i < n4; i += 256) {
    float4 v = s4[i];
    b4[i] = v;
    m = fmaxf(m, fmaxf(fmaxf(v.x, v.y), fmaxf(v.z, v.w)));
  }
  for (int off = 32; off > 0; off >>= 1) m = fmaxf(m, __shfl_xor(m, off));
  if ((tid & 63) == 0) red[tid >> 6] = m;
  __syncthreads();
  m = fmaxf(fmaxf(red[0], red[1]), fmaxf(red[2], red[3]));

  float sum = 0.f;
  for (int i = tid; i < n4; i += 256) {
    float4 v = b4[i];
    v.x = __expf(v.x - m); v.y = __expf(v.y - m);
    v.z = __expf(v.z - m); v.w = __expf(v.w - m);
    b4[i] = v;
    sum += (v.x + v.y) + (v.z + v.w);
  }
  for (int off = 32; off > 0; off >>= 1) sum += __shfl_xor(sum, off);
  if ((tid & 63) == 0) red[4 + (tid >> 6)] = sum;
  __syncthreads();
  sum = (red[4] + red[5]) + (red[6] + red[7]);
  const float inv = 1.f / sum;

  f16x4* p4 = (f16x4*)(P + (size_t)row * N);
  for (int i = tid; i < n4; i += 256) {
    float4 v = b4[i];
    f16x4 h = { (_Float16)(v.x * inv), (_Float16)(v.y * inv),
                (_Float16)(v.z * inv), (_Float16)(v.w * inv) };
    p4[i] = h;
  }
}

__global__ __launch_bounds__(256) void cast_f32_f16(const float* __restrict__ in,
                                                    _Float16* __restrict__ out, int n4) {
  int i = blockIdx.x * 256 + threadIdx.x;
  if (i < n4) {
    float4 v = ((const float4*)in)[i];
    f16x4 h = { (_Float16)v.x, (_Float16)v.y, (_Float16)v.z, (_Float16)v.w };
    ((f16x4*)out)[i] = h;
  }
}

// out[i] = sum of 4 split-K partials (deterministic)
__global__ __launch_bounds__(256) void reduce4(const float* __restrict__ p,
                                               float* __restrict__ out,
                                               int n4, size_t stride4) {
  int i = blockIdx.x * 256 + threadIdx.x;
  if (i >= n4) return;
  const float4* p4 = (const float4*)p;
  float4 a = p4[i];
  float4 b = p4[i + stride4];
  float4 c = p4[i + 2 * stride4];
  float4 d = p4[i + 3 * stride4];
  float4 r = { (a.x + b.x) + (c.x + d.x), (a.y + b.y) + (c.y + d.y),
               (a.z + b.z) + (c.z + d.z), (a.w + b.w) + (c.w + d.w) };
  ((float4*)out)[i] = r;
}

extern "C" void kernel_launch(void* const* d_in, const int* in_sizes, int n_in,
                              void* d_out, int out_size, void* d_ws, size_t ws_size,
                              hipStream_t stream) {
  const int D  = 1024;
  const int N1 = in_sizes[0] / D;   // 4096
  const int N2 = in_sizes[1] / D;   // 4096

  const float* x1 = (const float*)d_in[0];
  const float* x2 = (const float*)d_in[1];
  const float* Wq = (const float*)d_in[2];
  const float* Wk = (const float*)d_in[3];
  const float* Wv = (const float*)d_in[4];
  float* out = (float*)d_out;

  _Float16* x1h = (_Float16*)d_ws;
  _Float16* x2h = x1h + (size_t)N1 * D;
  _Float16* Wqh = x2h + (size_t)N2 * D;
  _Float16* Wkh = Wqh + (size_t)D * D;
  _Float16* Wvh = Wkh + (size_t)D * D;
  _Float16* Qh  = Wvh + (size_t)D * D;
  _Float16* Kh  = Qh  + (size_t)N1 * D;
  _Float16* Vt  = Kh  + (size_t)N2 * D;   // Vt[j,i] = V[i,j]
  _Float16* P   = Vt  + (size_t)D * N2;
  float*    S   = (float*)(P + (size_t)N1 * N2);  // 64MB; reused as PV partials

  auto cast = [&](const float* src, _Float16* dst, size_t n) {
    int n4 = (int)(n >> 2);
    cast_f32_f16<<<dim3((n4 + 255) / 256), 256, 0, stream>>>(src, dst, n4);
  };
  cast(x1, x1h, (size_t)N1 * D);
  cast(x2, x2h, (size_t)N2 * D);
  cast(Wq, Wqh, (size_t)D * D);
  cast(Wk, Wkh, (size_t)D * D);
  cast(Wv, Wvh, (size_t)D * D);

  // Fused QKV projections: one 192-block dispatch, 64 blocks per GEMM.
  {
    GDesc dq = { x1h, Wqh, Qh, D, D, D, N1 / 256, D / 256 };
    GDesc dk = { x2h, Wkh, Kh, D, D, D, N2 / 256, D / 256 };
    GDesc dv = { Wvh, x2h, Vt, D, D, N2, D / 256, N2 / 256 };
    gemmq<_Float16, true><<<dim3(192), 512, 0, stream>>>(dq, dk, dv, 64, D / 32, 0, 0);
  }
  // S = Q K^T [4096x4096] f32, grid 256 (1 block/CU)
  {
    GDesc dsd = { Qh, Kh, S, D, D, N2, N1 / 256, N2 / 256 };
    gemmq<float, false><<<dim3(256), 512, 0, stream>>>(dsd, dsd, dsd, 256, D / 32, 0, 0);
  }
  // P = softmax(S)
  softmax_rows<<<dim3(N1), 256, 0, stream>>>(S, P, N2);
  // PV split-K=4: partial[s] = P[:, s*1024:+1024] @ Vt[:, s*1024:+1024]^T
  {
    GDesc dp = { P, Vt, S, N2, N2, D, N1 / 256, D / 256 };
    gemmq<float, false><<<dim3(256), 512, 0, stream>>>(dp, dp, dp, 64, 1024 / 32, 1024,
                                                       (size_t)N1 * D);
  }
  reduce4<<<dim3((N1 * D / 4 + 255) / 256), 256, 0, stream>>>(
      S, out, N1 * D / 4, (size_t)N1 * D / 4);
}

// Round 7
// 160.526 us; speedup vs baseline: 1.6516x; 1.0119x over previous
//
#include <hip/hip_runtime.h>
#include <cstdint>
#include <cstddef>

typedef _Float16 f16x8 __attribute__((ext_vector_type(8)));
typedef _Float16 f16x4 __attribute__((ext_vector_type(4)));
typedef float f32x4 __attribute__((ext_vector_type(4)));

__device__ __forceinline__ void gload_lds16(const _Float16* g, void* l) {
  // async global->LDS, 16B/lane; LDS dest = wave-uniform base + lane*16
  __builtin_amdgcn_global_load_lds(
      (const __attribute__((address_space(1))) void*)(g),
      (__attribute__((address_space(3))) void*)(l), 16, 0, 0);
}

struct GDesc {
  const _Float16* A;  // [M][K] row-major, lda
  const _Float16* B;  // [N][K] row-major, ldb
  void* C;            // [M][N] row-major, ldc
  int lda, ldb, ldc, nbm, nbn;
};

struct QSet { f16x8 a[4]; f16x8 b[2]; };  // a03 (m0-3) + b01 (n0-1): 6 frags

#define MFMA16(d, va, vb) \
  d = __builtin_amdgcn_mfma_f32_16x16x32_f16(va, vb, d, 0, 0, 0)

// ---------------------------------------------------------------------------
// 256x256 NT GEMM, BK=32, 4 LDS buffers (128 KB), 8 waves (2M x 4N).
// R5: m201-style fine phases. Per K-tile: 4 phases x 8 MFMA (one output
// quadrant each), per-phase s_barrier, per-phase counted lgkmcnt (reads for
// phase p+1 issued during phase p; never drained), 1 gload_lds per phase
// (tile t+3), vmcnt(8) once per tile. setprio(1) around each MFMA cluster.
// Zero-conflict XOR swizzle (R2-R4 verified, SQ_LDS_BANK_CONFLICT=0):
// phys 16B slot p = q ^ ((row>>1)&3) on both global src and ds_read.
// lgkm ledger (in-order DS queue, per wave):
//   [t-1.ph2: 6 (a03,b01 of t)] -> ph0 issues 2 (b23), lgkm(2) waits the 6
//   -> ph1 issues 4 (a47), lgkm(4) waits b23
//   -> ph2 issues 6 (next a03,b01), lgkm(6) waits a47 -> ph3 issues 0.
// ---------------------------------------------------------------------------
__device__ __forceinline__ void tile_body(
    int t, int nKT, QSet& cur, QSet& nxt, char* smem,
    const _Float16* gA0, const _Float16* gA1,
    const _Float16* gB0, const _Float16* gB1,
    int w, int aBase, int bBase, f32x4 (&acc)[8][4]) {
  const char* Ab = smem + (t & 3) * 32768;
  const char* Bb = Ab + 16384;
  const int jc = (t + 3 < nKT) ? t + 3 : nKT - 1;  // clamped tail: re-stage
  char* dst = smem + (jc & 3) * 32768;
  const char* AbN = smem + ((t + 1) & 3) * 32768;  // stale at t==nKT-1: unused
  const char* BbN = AbN + 16384;

  f16x8 b23[2], a47[4];

  // ---- ph0: Q0 = a03 x b01 ----
  asm volatile("s_waitcnt vmcnt(8)" ::: "memory");  // tile t landed
  __builtin_amdgcn_s_barrier();  // all waves done reading buf (t-1): WAR ok
  gload_lds16(gA0 + jc * 32, dst + (w << 10));
  b23[0] = *(const f16x8*)(Bb + bBase + (2 << 10));
  b23[1] = *(const f16x8*)(Bb + bBase + (3 << 10));
  asm volatile("s_waitcnt lgkmcnt(2)" ::: "memory");  // a03,b01(t) ready
  __builtin_amdgcn_sched_barrier(0);
  __builtin_amdgcn_s_setprio(1);
#pragma unroll
  for (int m = 0; m < 4; ++m)
#pragma unroll
    for (int n = 0; n < 2; ++n) MFMA16(acc[m][n], cur.a[m], cur.b[n]);
  __builtin_amdgcn_s_setprio(0);

  // ---- ph1: Q1 = a03 x b23 ----
  __builtin_amdgcn_s_barrier();
  gload_lds16(gA1 + jc * 32, dst + ((w + 8) << 10));
#pragma unroll
  for (int m = 0; m < 4; ++m)
    a47[m] = *(const f16x8*)(Ab + aBase + ((m + 4) << 10));
  asm volatile("s_waitcnt lgkmcnt(4)" ::: "memory");  // b23 ready
  __builtin_amdgcn_sched_barrier(0);
  __builtin_amdgcn_s_setprio(1);
#pragma unroll
  for (int m = 0; m < 4; ++m)
#pragma unroll
    for (int n = 0; n < 2; ++n) MFMA16(acc[m][n + 2], cur.a[m], b23[n]);
  __builtin_amdgcn_s_setprio(0);

  // ---- ph2: Q2 = a47 x b01 ----
  __builtin_amdgcn_s_barrier();
  gload_lds16(gB0 + jc * 32, dst + 16384 + (w << 10));
#pragma unroll
  for (int m = 0; m < 4; ++m)
    nxt.a[m] = *(const f16x8*)(AbN + aBase + (m << 10));
#pragma unroll
  for (int n = 0; n < 2; ++n)
    nxt.b[n] = *(const f16x8*)(BbN + bBase + (n << 10));
  asm volatile("s_waitcnt lgkmcnt(6)" ::: "memory");  // a47 ready
  __builtin_amdgcn_sched_barrier(0);
  __builtin_amdgcn_s_setprio(1);
#pragma unroll
  for (int m = 0; m < 4; ++m)
#pragma unroll
    for (int n = 0; n < 2; ++n) MFMA16(acc[m + 4][n], a47[m], cur.b[n]);
  __builtin_amdgcn_s_setprio(0);

  // ---- ph3: Q3 = a47 x b23 (operands already waited) ----
  __builtin_amdgcn_s_barrier();
  gload_lds16(gB1 + jc * 32, dst + 16384 + ((w + 8) << 10));
  __builtin_amdgcn_s_setprio(1);
#pragma unroll
  for (int m = 0; m < 4; ++m)
#pragma unroll
    for (int n = 0; n < 2; ++n) MFMA16(acc[m + 4][n + 2], a47[m], b23[n]);
  __builtin_amdgcn_s_setprio(0);
}

template <typename CT, bool MULTI>
__global__ __launch_bounds__(512, 2) void gemmq(
    GDesc d0, GDesc d1, GDesc d2,
    int inner, int nKT, int ksOff, size_t cSplit) {
  __shared__ __align__(16) char smem[131072];  // 4 bufs x (A 16KB | B 16KB)

  const int bid = blockIdx.x;
  const int gi  = bid / inner;
  int ib        = bid % inner;

  GDesc d = d0;
  if (MULTI) { if (gi == 1) d = d1; else if (gi == 2) d = d2; }
  const _Float16* A = d.A;
  const _Float16* B = d.B;
  CT* C = (CT*)d.C;
  if (!MULTI) {
    A += (size_t)gi * ksOff;
    B += (size_t)gi * ksOff;
    C += (size_t)gi * cSplit;
  }
  const int lda = d.lda, ldb = d.ldb, ldc = d.ldc, nbn = d.nbn;

  // XCD-aware swizzle (inner % 8 == 0 for all launches)
  ib = (ib & 7) * (inner >> 3) + (ib >> 3);
  const int brow = (ib / nbn) << 8;
  const int bcol = (ib % nbn) << 8;

  const int tid = threadIdx.x;
  const int w   = tid >> 6;   // 0..7
  const int l   = tid & 63;
  const int wm  = w >> 2;     // 0..1
  const int wn  = w & 3;      // 0..3

  // staging: chunk = 16 rows x 64B; wave w stages chunks {w, w+8} of A and B.
  // lane l -> row_in_chunk = l>>2, phys slot = l&3; global logical slot
  // q = (l&3) ^ ((l>>3)&3)  [inverse of read swizzle].
  const int sRow = l >> 2;
  const int sCol = (((l & 3) ^ ((l >> 3) & 3)) << 3);
  const _Float16* gA0 = A + (size_t)(brow + (w << 4) + sRow) * lda + sCol;
  const _Float16* gA1 = A + (size_t)(brow + ((w + 8) << 4) + sRow) * lda + sCol;
  const _Float16* gB0 = B + (size_t)(bcol + (w << 4) + sRow) * ldb + sCol;
  const _Float16* gB1 = B + (size_t)(bcol + ((w + 8) << 4) + sRow) * ldb + sCol;

  // fragment read offsets (swizzled): frag row r=l&15, kslot l>>4:
  // byte = r*64 + ((l>>4) ^ ((r>>1)&3))*16
  const int axr = (l >> 1) & 3;
  const int fq  = ((l >> 4) ^ axr) << 4;
  const int aBase = (wm << 13) + ((l & 15) << 6) + fq;
  const int bBase = (wn << 12) + ((l & 15) << 6) + fq;

  f32x4 acc[8][4] = {};
  QSet s0, s1;

  // prologue: stage tiles 0,1,2
#pragma unroll
  for (int tt = 0; tt < 3; ++tt) {
    char* dst = smem + tt * 32768;
    gload_lds16(gA0 + tt * 32, dst + (w << 10));
    gload_lds16(gA1 + tt * 32, dst + ((w + 8) << 10));
    gload_lds16(gB0 + tt * 32, dst + 16384 + (w << 10));
    gload_lds16(gB1 + tt * 32, dst + 16384 + ((w + 8) << 10));
  }
  asm volatile("s_waitcnt vmcnt(8)" ::: "memory");  // tile 0 landed (own part)
  __builtin_amdgcn_s_barrier();                     // everyone's part landed
  {
    const char* Ab = smem;
    const char* Bb = smem + 16384;
#pragma unroll
    for (int m = 0; m < 4; ++m) s0.a[m] = *(const f16x8*)(Ab + aBase + (m << 10));
#pragma unroll
    for (int n = 0; n < 2; ++n) s0.b[n] = *(const f16x8*)(Bb + bBase + (n << 10));
    // left outstanding (6); tile 0 ph0's lgkm(2) waits them
  }

  for (int t = 0; t < nKT; t += 2) {  // nKT even
    tile_body(t,     nKT, s0, s1, smem, gA0, gA1, gB0, gB1, w, aBase, bBase, acc);
    tile_body(t + 1, nKT, s1, s0, smem, gA0, gA1, gB0, gB1, w, aBase, bBase, acc);
  }
  asm volatile("s_waitcnt vmcnt(0) lgkmcnt(0)" ::: "memory");

  // epilogue: C/D layout col=lane&15, row=(lane>>4)*4+jj
  const int crow0 = brow + (wm << 7) + ((l >> 4) << 2);
  const int ccol  = bcol + (wn << 6) + (l & 15);
#pragma unroll
  for (int m = 0; m < 8; ++m)
#pragma unroll
    for (int n = 0; n < 4; ++n)
#pragma unroll
      for (int jj = 0; jj < 4; ++jj)
        C[(size_t)(crow0 + (m << 4) + jj) * ldc + ccol + (n << 4)] = (CT)acc[m][n][jj];
}

// Row softmax: S[row, 0..N) f32 -> P fp16.
__global__ __launch_bounds__(256) void softmax_rows(const float* __restrict__ S,
                                                    _Float16* __restrict__ P,
                                                    int N) {
  __shared__ float buf[4096];
  __shared__ float red[8];
  const int row = blockIdx.x;
  const int tid = threadIdx.x;
  const int n4  = N >> 2;
  const float4* s4 = (const float4*)(S + (size_t)row * N);
  float4* b4 = (float4*)buf;

  float m = -3.4e38f;
  for (int i = tid; i < n4; i += 256) {
    float4 v = s4[i];
    b4[i] = v;
    m = fmaxf(m, fmaxf(fmaxf(v.x, v.y), fmaxf(v.z, v.w)));
  }
  for (int off = 32; off > 0; off >>= 1) m = fmaxf(m, __shfl_xor(m, off));
  if ((tid & 63) == 0) red[tid >> 6] = m;
  __syncthreads();
  m = fmaxf(fmaxf(red[0], red[1]), fmaxf(red[2], red[3]));

  float sum = 0.f;
  for (int i = tid; i < n4; i += 256) {
    float4 v = b4[i];
    v.x = __expf(v.x - m); v.y = __expf(v.y - m);
    v.z = __expf(v.z - m); v.w = __expf(v.w - m);
    b4[i] = v;
    sum += (v.x + v.y) + (v.z + v.w);
  }
  for (int off = 32; off > 0; off >>= 1) sum += __shfl_xor(sum, off);
  if ((tid & 63) == 0) red[4 + (tid >> 6)] = sum;
  __syncthreads();
  sum = (red[4] + red[5]) + (red[6] + red[7]);
  const float inv = 1.f / sum;

  f16x4* p4 = (f16x4*)(P + (size_t)row * N);
  for (int i = tid; i < n4; i += 256) {
    float4 v = b4[i];
    f16x4 h = { (_Float16)(v.x * inv), (_Float16)(v.y * inv),
                (_Float16)(v.z * inv), (_Float16)(v.w * inv) };
    p4[i] = h;
  }
}

__global__ __launch_bounds__(256) void cast_f32_f16(const float* __restrict__ in,
                                                    _Float16* __restrict__ out, int n4) {
  int i = blockIdx.x * 256 + threadIdx.x;
  if (i < n4) {
    float4 v = ((const float4*)in)[i];
    f16x4 h = { (_Float16)v.x, (_Float16)v.y, (_Float16)v.z, (_Float16)v.w };
    ((f16x4*)out)[i] = h;
  }
}

// out[i] = sum of 4 split-K partials (deterministic)
__global__ __launch_bounds__(256) void reduce4(const float* __restrict__ p,
                                               float* __restrict__ out,
                                               int n4, size_t stride4) {
  int i = blockIdx.x * 256 + threadIdx.x;
  if (i >= n4) return;
  const float4* p4 = (const float4*)p;
  float4 a = p4[i];
  float4 b = p4[i + stride4];
  float4 c = p4[i + 2 * stride4];
  float4 d = p4[i + 3 * stride4];
  float4 r = { (a.x + b.x) + (c.x + d.x), (a.y + b.y) + (c.y + d.y),
               (a.z + b.z) + (c.z + d.z), (a.w + b.w) + (c.w + d.w) };
  ((float4*)out)[i] = r;
}

extern "C" void kernel_launch(void* const* d_in, const int* in_sizes, int n_in,
                              void* d_out, int out_size, void* d_ws, size_t ws_size,
                              hipStream_t stream) {
  const int D  = 1024;
  const int N1 = in_sizes[0] / D;   // 4096
  const int N2 = in_sizes[1] / D;   // 4096

  const float* x1 = (const float*)d_in[0];
  const float* x2 = (const float*)d_in[1];
  const float* Wq = (const float*)d_in[2];
  const float* Wk = (const float*)d_in[3];
  const float* Wv = (const float*)d_in[4];
  float* out = (float*)d_out;

  _Float16* x1h = (_Float16*)d_ws;
  _Float16* x2h = x1h + (size_t)N1 * D;
  _Float16* Wqh = x2h + (size_t)N2 * D;
  _Float16* Wkh = Wqh + (size_t)D * D;
  _Float16* Wvh = Wkh + (size_t)D * D;
  _Float16* Qh  = Wvh + (size_t)D * D;
  _Float16* Kh  = Qh  + (size_t)N1 * D;
  _Float16* Vt  = Kh  + (size_t)N2 * D;   // Vt[j,i] = V[i,j]
  _Float16* P   = Vt  + (size_t)D * N2;
  float*    S   = (float*)(P + (size_t)N1 * N2);  // 64MB; reused as PV partials

  auto cast = [&](const float* src, _Float16* dst, size_t n) {
    int n4 = (int)(n >> 2);
    cast_f32_f16<<<dim3((n4 + 255) / 256), 256, 0, stream>>>(src, dst, n4);
  };
  cast(x1, x1h, (size_t)N1 * D);
  cast(x2, x2h, (size_t)N2 * D);
  cast(Wq, Wqh, (size_t)D * D);
  cast(Wk, Wkh, (size_t)D * D);
  cast(Wv, Wvh, (size_t)D * D);

  // Fused QKV projections: one 192-block dispatch, 64 blocks per GEMM.
  {
    GDesc dq = { x1h, Wqh, Qh, D, D, D, N1 / 256, D / 256 };
    GDesc dk = { x2h, Wkh, Kh, D, D, D, N2 / 256, D / 256 };
    GDesc dv = { Wvh, x2h, Vt, D, D, N2, D / 256, N2 / 256 };
    gemmq<_Float16, true><<<dim3(192), 512, 0, stream>>>(dq, dk, dv, 64, D / 32, 0, 0);
  }
  // S = Q K^T [4096x4096] f32, grid 256 (1 block/CU)
  {
    GDesc dsd = { Qh, Kh, S, D, D, N2, N1 / 256, N2 / 256 };
    gemmq<float, false><<<dim3(256), 512, 0, stream>>>(dsd, dsd, dsd, 256, D / 32, 0, 0);
  }
  // P = softmax(S)
  softmax_rows<<<dim3(N1), 256, 0, stream>>>(S, P, N2);
  // PV split-K=4: partial[s] = P[:, s*1024:+1024] @ Vt[:, s*1024:+1024]^T
  {
    GDesc dp = { P, Vt, S, N2, N2, D, N1 / 256, D / 256 };
    gemmq<float, false><<<dim3(256), 512, 0, stream>>>(dp, dp, dp, 64, 1024 / 32, 1024,
                                                       (size_t)N1 * D);
  }
  reduce4<<<dim3((N1 * D / 4 + 255) / 256), 256, 0, stream>>>(
      S, out, N1 * D / 4, (size_t)N1 * D / 4);
}

// Round 8
// 160.415 us; speedup vs baseline: 1.6527x; 1.0007x over previous
//
#include <hip/hip_runtime.h>
#include <cstdint>
#include <cstddef>

typedef _Float16 f16x8 __attribute__((ext_vector_type(8)));
typedef _Float16 f16x4 __attribute__((ext_vector_type(4)));
typedef float f32x4 __attribute__((ext_vector_type(4)));

__device__ __forceinline__ void gload_lds16(const _Float16* g, void* l) {
  // async global->LDS, 16B/lane; LDS dest = wave-uniform base + lane*16
  __builtin_amdgcn_global_load_lds(
      (const __attribute__((address_space(1))) void*)(g),
      (__attribute__((address_space(3))) void*)(l), 16, 0, 0);
}

struct GDesc {
  const _Float16* A;  // [M][K] row-major, lda
  const _Float16* B;  // [N][K] row-major, ldb
  void* C;            // [M][N] row-major, ldc
  int lda, ldb, ldc, nbm, nbn;
};

// Full tile-t fragment set, double-buffered across tiles (rule 20: two named
// sets swapped by a 2x-unrolled loop; all indexing compile-time).
struct FSet { f16x8 b[4]; f16x8 a0[4]; f16x8 a1[4]; };  // 12 frags = 48 VGPR

#define MFMA16(d, va, vb) \
  d = __builtin_amdgcn_mfma_f32_16x16x32_f16(va, vb, d, 0, 0, 0)

// ---------------------------------------------------------------------------
// 256x256 NT GEMM, BK=32, 4 LDS buffers (128 KB), 8 waves (2M x 4N).
// R8: tile-ahead register pipeline. All 12 ds_reads of tile t+1 are issued
// DURING tile t (grp1={b,a03} in ph0, grp2={a47} in ph1) into the alternate
// FSet; waits target reads issued a FULL TILE (~1200 cyc) earlier:
//   ph0: lgkm(4)  -> grp1(t) done (grp2(t)=4 newest remain)
//   ph1: lgkm(8)  -> grp2(t) done (grp1(t+1)=8 newest remain)
// Peak 12 lgkm outstanding (<=15 HW limit). gloads are vmcnt-only.
// vmcnt ledger unchanged (4 gloads/tile, vmcnt(8) at tile entry = tile t
// landed, 2 tiles in flight). One barrier per tile (WAR: staging writes buf
// (t-1)&3, whose reads completed at tile t-1's lgkm waits on every wave).
// Tail: clamped re-stage is byte-identical (benign); tile-nKT frag reads hit
// stale buf (values unused, counts consistent).
// Zero-conflict XOR swizzle (R2-R7 verified, SQ_LDS_BANK_CONFLICT=0).
// ---------------------------------------------------------------------------
__device__ __forceinline__ void tile_body(
    int t, int nKT, FSet& cur, FSet& nxt, char* smem,
    const _Float16* gA0, const _Float16* gA1,
    const _Float16* gB0, const _Float16* gB1,
    int w, int aBase, int bBase, f32x4 (&acc)[8][4]) {
  const int jc = (t + 3 < nKT) ? t + 3 : nKT - 1;  // clamped tail re-stage
  char* dst = smem + (jc & 3) * 32768;
  const char* AbN = smem + ((t + 1) & 3) * 32768;  // stale at t==nKT-1: unused
  const char* BbN = AbN + 16384;

  // ---- ph0: MFMA m0-3 x n0-3 (a03 x b) ----
  asm volatile("s_waitcnt vmcnt(8)" ::: "memory");  // tile t staged
  __builtin_amdgcn_s_barrier();  // all waves' reads of buf (t-1) retired: WAR ok
  gload_lds16(gA0 + jc * 32, dst + (w << 10));
  gload_lds16(gA1 + jc * 32, dst + ((w + 8) << 10));
  asm volatile("s_waitcnt lgkmcnt(4)" ::: "memory");  // grp1(t) ready
  __builtin_amdgcn_sched_barrier(0);
#pragma unroll
  for (int n = 0; n < 4; ++n) nxt.b[n]  = *(const f16x8*)(BbN + bBase + (n << 10));
#pragma unroll
  for (int m = 0; m < 4; ++m) nxt.a0[m] = *(const f16x8*)(AbN + aBase + (m << 10));
  __builtin_amdgcn_sched_barrier(0);
  __builtin_amdgcn_s_setprio(1);
#pragma unroll
  for (int m = 0; m < 4; ++m)
#pragma unroll
    for (int n = 0; n < 4; ++n) MFMA16(acc[m][n], cur.a0[m], cur.b[n]);
  __builtin_amdgcn_s_setprio(0);

  // ---- ph1: MFMA m4-7 x n0-3 (a47 x b) ----
  gload_lds16(gB0 + jc * 32, dst + 16384 + (w << 10));
  gload_lds16(gB1 + jc * 32, dst + 16384 + ((w + 8) << 10));
  asm volatile("s_waitcnt lgkmcnt(8)" ::: "memory");  // grp2(t) ready
  __builtin_amdgcn_sched_barrier(0);
#pragma unroll
  for (int m = 0; m < 4; ++m) nxt.a1[m] = *(const f16x8*)(AbN + aBase + ((m + 4) << 10));
  __builtin_amdgcn_sched_barrier(0);
  __builtin_amdgcn_s_setprio(1);
#pragma unroll
  for (int m = 0; m < 4; ++m)
#pragma unroll
    for (int n = 0; n < 4; ++n) MFMA16(acc[m + 4][n], cur.a1[m], cur.b[n]);
  __builtin_amdgcn_s_setprio(0);
}

template <typename CT, bool MULTI>
__global__ __launch_bounds__(512, 2) void gemmq(
    GDesc d0, GDesc d1, GDesc d2,
    int inner, int nKT, int ksOff, size_t cSplit) {
  __shared__ __align__(16) char smem[131072];  // 4 bufs x (A 16KB | B 16KB)

  const int bid = blockIdx.x;
  const int gi  = bid / inner;
  int ib        = bid % inner;

  GDesc d = d0;
  if (MULTI) { if (gi == 1) d = d1; else if (gi == 2) d = d2; }
  const _Float16* A = d.A;
  const _Float16* B = d.B;
  CT* C = (CT*)d.C;
  if (!MULTI) {
    A += (size_t)gi * ksOff;
    B += (size_t)gi * ksOff;
    C += (size_t)gi * cSplit;
  }
  const int lda = d.lda, ldb = d.ldb, ldc = d.ldc, nbn = d.nbn;

  // XCD-aware swizzle (inner % 8 == 0 for all launches)
  ib = (ib & 7) * (inner >> 3) + (ib >> 3);
  const int brow = (ib / nbn) << 8;
  const int bcol = (ib % nbn) << 8;

  const int tid = threadIdx.x;
  const int w   = tid >> 6;   // 0..7
  const int l   = tid & 63;
  const int wm  = w >> 2;     // 0..1
  const int wn  = w & 3;      // 0..3

  // staging: chunk = 16 rows x 64B; wave w stages chunks {w, w+8} of A and B.
  // lane l -> row_in_chunk = l>>2, phys slot = l&3; global logical slot
  // q = (l&3) ^ ((l>>3)&3)  [inverse of read swizzle].
  const int sRow = l >> 2;
  const int sCol = (((l & 3) ^ ((l >> 3) & 3)) << 3);
  const _Float16* gA0 = A + (size_t)(brow + (w << 4) + sRow) * lda + sCol;
  const _Float16* gA1 = A + (size_t)(brow + ((w + 8) << 4) + sRow) * lda + sCol;
  const _Float16* gB0 = B + (size_t)(bcol + (w << 4) + sRow) * ldb + sCol;
  const _Float16* gB1 = B + (size_t)(bcol + ((w + 8) << 4) + sRow) * ldb + sCol;

  // fragment read offsets (swizzled): frag row r=l&15, kslot l>>4:
  // byte = r*64 + ((l>>4) ^ ((r>>1)&3))*16
  const int axr = (l >> 1) & 3;
  const int fq  = ((l >> 4) ^ axr) << 4;
  const int aBase = (wm << 13) + ((l & 15) << 6) + fq;
  const int bBase = (wn << 12) + ((l & 15) << 6) + fq;

  f32x4 acc[8][4] = {};
  FSet s0, s1;

  // prologue: stage tiles 0,1,2
#pragma unroll
  for (int tt = 0; tt < 3; ++tt) {
    char* dst = smem + tt * 32768;
    gload_lds16(gA0 + tt * 32, dst + (w << 10));
    gload_lds16(gA1 + tt * 32, dst + ((w + 8) << 10));
    gload_lds16(gB0 + tt * 32, dst + 16384 + (w << 10));
    gload_lds16(gB1 + tt * 32, dst + 16384 + ((w + 8) << 10));
  }
  asm volatile("s_waitcnt vmcnt(8)" ::: "memory");  // tile 0 landed (own part)
  __builtin_amdgcn_s_barrier();                     // everyone's part landed
  {
    // issue tile-0 frags (12 reads outstanding; tile-0 waits drain them)
    const char* Ab = smem;
    const char* Bb = smem + 16384;
#pragma unroll
    for (int n = 0; n < 4; ++n) s0.b[n]  = *(const f16x8*)(Bb + bBase + (n << 10));
#pragma unroll
    for (int m = 0; m < 4; ++m) s0.a0[m] = *(const f16x8*)(Ab + aBase + (m << 10));
#pragma unroll
    for (int m = 0; m < 4; ++m) s0.a1[m] = *(const f16x8*)(Ab + aBase + ((m + 4) << 10));
  }

  for (int t = 0; t < nKT; t += 2) {  // nKT even, >= 4
    tile_body(t,     nKT, s0, s1, smem, gA0, gA1, gB0, gB1, w, aBase, bBase, acc);
    tile_body(t + 1, nKT, s1, s0, smem, gA0, gA1, gB0, gB1, w, aBase, bBase, acc);
  }
  asm volatile("s_waitcnt vmcnt(0) lgkmcnt(0)" ::: "memory");

  // epilogue: C/D layout col=lane&15, row=(lane>>4)*4+jj
  const int crow0 = brow + (wm << 7) + ((l >> 4) << 2);
  const int ccol  = bcol + (wn << 6) + (l & 15);
#pragma unroll
  for (int m = 0; m < 8; ++m)
#pragma unroll
    for (int n = 0; n < 4; ++n)
#pragma unroll
      for (int jj = 0; jj < 4; ++jj)
        C[(size_t)(crow0 + (m << 4) + jj) * ldc + ccol + (n << 4)] = (CT)acc[m][n][jj];
}

// Row softmax: S[row, 0..N) f32 -> P fp16.
__global__ __launch_bounds__(256) void softmax_rows(const float* __restrict__ S,
                                                    _Float16* __restrict__ P,
                                                    int N) {
  __shared__ float buf[4096];
  __shared__ float red[8];
  const int row = blockIdx.x;
  const int tid = threadIdx.x;
  const int n4  = N >> 2;
  const float4* s4 = (const float4*)(S + (size_t)row * N);
  float4* b4 = (float4*)buf;

  float m = -3.4e38f;
  for (int i = tid; i < n4; i += 256) {
    float4 v = s4[i];
    b4[i] = v;
    m = fmaxf(m, fmaxf(fmaxf(v.x, v.y), fmaxf(v.z, v.w)));
  }
  for (int off = 32; off > 0; off >>= 1) m = fmaxf(m, __shfl_xor(m, off));
  if ((tid & 63) == 0) red[tid >> 6] = m;
  __syncthreads();
  m = fmaxf(fmaxf(red[0], red[1]), fmaxf(red[2], red[3]));

  float sum = 0.f;
  for (int i = tid; i < n4; i += 256) {
    float4 v = b4[i];
    v.x = __expf(v.x - m); v.y = __expf(v.y - m);
    v.z = __expf(v.z - m); v.w = __expf(v.w - m);
    b4[i] = v;
    sum += (v.x + v.y) + (v.z + v.w);
  }
  for (int off = 32; off > 0; off >>= 1) sum += __shfl_xor(sum, off);
  if ((tid & 63) == 0) red[4 + (tid >> 6)] = sum;
  __syncthreads();
  sum = (red[4] + red[5]) + (red[6] + red[7]);
  const float inv = 1.f / sum;

  f16x4* p4 = (f16x4*)(P + (size_t)row * N);
  for (int i = tid; i < n4; i += 256) {
    float4 v = b4[i];
    f16x4 h = { (_Float16)(v.x * inv), (_Float16)(v.y * inv),
                (_Float16)(v.z * inv), (_Float16)(v.w * inv) };
    p4[i] = h;
  }
}

__global__ __launch_bounds__(256) void cast_f32_f16(const float* __restrict__ in,
                                                    _Float16* __restrict__ out, int n4) {
  int i = blockIdx.x * 256 + threadIdx.x;
  if (i < n4) {
    float4 v = ((const float4*)in)[i];
    f16x4 h = { (_Float16)v.x, (_Float16)v.y, (_Float16)v.z, (_Float16)v.w };
    ((f16x4*)out)[i] = h;
  }
}

// out[i] = sum of 4 split-K partials (deterministic)
__global__ __launch_bounds__(256) void reduce4(const float* __restrict__ p,
                                               float* __restrict__ out,
                                               int n4, size_t stride4) {
  int i = blockIdx.x * 256 + threadIdx.x;
  if (i >= n4) return;
  const float4* p4 = (const float4*)p;
  float4 a = p4[i];
  float4 b = p4[i + stride4];
  float4 c = p4[i + 2 * stride4];
  float4 d = p4[i + 3 * stride4];
  float4 r = { (a.x + b.x) + (c.x + d.x), (a.y + b.y) + (c.y + d.y),
               (a.z + b.z) + (c.z + d.z), (a.w + b.w) + (c.w + d.w) };
  ((float4*)out)[i] = r;
}

extern "C" void kernel_launch(void* const* d_in, const int* in_sizes, int n_in,
                              void* d_out, int out_size, void* d_ws, size_t ws_size,
                              hipStream_t stream) {
  const int D  = 1024;
  const int N1 = in_sizes[0] / D;   // 4096
  const int N2 = in_sizes[1] / D;   // 4096

  const float* x1 = (const float*)d_in[0];
  const float* x2 = (const float*)d_in[1];
  const float* Wq = (const float*)d_in[2];
  const float* Wk = (const float*)d_in[3];
  const float* Wv = (const float*)d_in[4];
  float* out = (float*)d_out;

  _Float16* x1h = (_Float16*)d_ws;
  _Float16* x2h = x1h + (size_t)N1 * D;
  _Float16* Wqh = x2h + (size_t)N2 * D;
  _Float16* Wkh = Wqh + (size_t)D * D;
  _Float16* Wvh = Wkh + (size_t)D * D;
  _Float16* Qh  = Wvh + (size_t)D * D;
  _Float16* Kh  = Qh  + (size_t)N1 * D;
  _Float16* Vt  = Kh  + (size_t)N2 * D;   // Vt[j,i] = V[i,j]
  _Float16* P   = Vt  + (size_t)D * N2;
  float*    S   = (float*)(P + (size_t)N1 * N2);  // 64MB; reused as PV partials

  auto cast = [&](const float* src, _Float16* dst, size_t n) {
    int n4 = (int)(n >> 2);
    cast_f32_f16<<<dim3((n4 + 255) / 256), 256, 0, stream>>>(src, dst, n4);
  };
  cast(x1, x1h, (size_t)N1 * D);
  cast(x2, x2h, (size_t)N2 * D);
  cast(Wq, Wqh, (size_t)D * D);
  cast(Wk, Wkh, (size_t)D * D);
  cast(Wv, Wvh, (size_t)D * D);

  // Fused QKV projections: one 192-block dispatch, 64 blocks per GEMM.
  {
    GDesc dq = { x1h, Wqh, Qh, D, D, D, N1 / 256, D / 256 };
    GDesc dk = { x2h, Wkh, Kh, D, D, D, N2 / 256, D / 256 };
    GDesc dv = { Wvh, x2h, Vt, D, D, N2, D / 256, N2 / 256 };
    gemmq<_Float16, true><<<dim3(192), 512, 0, stream>>>(dq, dk, dv, 64, D / 32, 0, 0);
  }
  // S = Q K^T [4096x4096] f32, grid 256 (1 block/CU)
  {
    GDesc dsd = { Qh, Kh, S, D, D, N2, N1 / 256, N2 / 256 };
    gemmq<float, false><<<dim3(256), 512, 0, stream>>>(dsd, dsd, dsd, 256, D / 32, 0, 0);
  }
  // P = softmax(S)
  softmax_rows<<<dim3(N1), 256, 0, stream>>>(S, P, N2);
  // PV split-K=4: partial[s] = P[:, s*1024:+1024] @ Vt[:, s*1024:+1024]^T
  {
    GDesc dp = { P, Vt, S, N2, N2, D, N1 / 256, D / 256 };
    gemmq<float, false><<<dim3(256), 512, 0, stream>>>(dp, dp, dp, 64, 1024 / 32, 1024,
                                                       (size_t)N1 * D);
  }
  reduce4<<<dim3((N1 * D / 4 + 255) / 256), 256, 0, stream>>>(
      S, out, N1 * D / 4, (size_t)N1 * D / 4);
}